// Round 9
// baseline (328.497 us; speedup 1.0000x reference)
//
#include <hip/hip_runtime.h>
#include <math.h>

// LDS geometry (8x4 px tile, 6x10 halo patch)
#define PSTR  40            // fp16 patch cell stride: 80 B
#define GSTR  35            // gate-exchange row stride (floats; odd -> ~2-way banks)
#define GPL32 (32 * GSTR)   // one gate plane: 32 px x GSTR floats

typedef _Float16 half8 __attribute__((ext_vector_type(8)));
typedef _Float16 half4 __attribute__((ext_vector_type(4)));
typedef float    f32x4 __attribute__((ext_vector_type(4)));

__device__ __forceinline__ float fast_tanh(float v) {
    float e = __expf(2.f * v);
    return 1.f - 2.f / (e + 1.f);
}
__device__ __forceinline__ float hsig(float v) {
    return fminf(fmaxf(0.2f * v + 0.5f, 0.f), 1.f);
}
__device__ __forceinline__ int div10(int p) { return (p * 205) >> 11; }  // p < 1024

// Pack weights: Wcx[tap][n][ci<32] from Wx[tap][ci][n]; Wch[tap][n][ci] from Wh[tap][ci][n]
__global__ void prep_w(const float* __restrict__ Wx, const float* __restrict__ Wh,
                       _Float16* __restrict__ Wcx, _Float16* __restrict__ Wch) {
    const int k = blockIdx.x;      // 0..575 = tap*64 + ci
    const int n = threadIdx.x;     // 0..127
    const int tap = k >> 6, ci = k & 63;
    if (ci < 32) Wcx[(tap * 128 + n) * 32 + ci]        = (_Float16)Wx[(tap * 32 + ci) * 128 + n];
    else         Wch[(tap * 128 + n) * 32 + (ci - 32)] = (_Float16)Wh[(tap * 32 + (ci - 32)) * 128 + n];
}

// One fused timestep per launch. 8x4 px tiles -> 1024 blocks -> 4 blocks/CU
// (16 waves/CU, 4 waves/SIMD) for latency hiding. N-split waves: wave w = gate w
// over all 32 px (2 m-tiles x 2 n-tiles); 36 B-frag loads / 72 MFMA per wave.
// Gates exchanged via padded LDS; epilogue thread (px=tid>>3, f0=(tid&7)*4) does
// LSTM+BN with coalesced h/c/out writes. Grid (8,8,16): blockIdx.x = batch.
__global__ __launch_bounds__(256, 4)
void lstm_step_k(const float* __restrict__ x, const _Float16* __restrict__ Wcx,
                 const _Float16* __restrict__ Wch, const float* __restrict__ bias,
                 const float* __restrict__ gamma_, const float* __restrict__ beta_,
                 const float* __restrict__ mmean, const float* __restrict__ mvar,
                 const _Float16* __restrict__ hprev, _Float16* __restrict__ hnext,
                 float* __restrict__ csw, float* __restrict__ out, int t)
{
    __shared__ _Float16 xp[60 * PSTR];    // 4.8 KB: 6x10 halo x 32 x-ch
    __shared__ _Float16 hp[60 * PSTR];    // 4.8 KB: 6x10 halo x 32 h-ch
    __shared__ float    glds[4 * GPL32];  // 17.9 KB: gate exchange [gate][px][f]

    const int tid  = threadIdx.x;
    const int lane = tid & 63;
    const int w    = tid >> 6;            // wave index == gate (i,f,c,o)
    const int l15  = lane & 15, quad = lane >> 4;
    const int b = blockIdx.x, tx = blockIdx.y, ty = blockIdx.z;
    const int px0 = tx * 8, py0 = ty * 4;
    const int tile = ty * 8 + tx;         // 0..127

    // ---- stage x patch (fp32 -> fp16) and h patch (fp16): one item per thread ----
    const float* xt = x + (((size_t)b * 16 + t) * 4096) * 32;
    if (tid < 240) {                      // 60 cells x 4 chunks
        const int cell = tid >> 2, q = tid & 3;
        const int row = div10(cell), col = cell - row * 10;
        const int gy = py0 + row - 1, gx = px0 + col - 1;
        half8 hv = {0, 0, 0, 0, 0, 0, 0, 0};
        if ((unsigned)gy < 64u && (unsigned)gx < 64u) {
            const float* s = xt + ((size_t)(gy * 64 + gx)) * 32 + q * 8;
            const float4 v0 = *(const float4*)s;
            const float4 v1 = *(const float4*)(s + 4);
            hv = (half8){(_Float16)v0.x, (_Float16)v0.y, (_Float16)v0.z, (_Float16)v0.w,
                         (_Float16)v1.x, (_Float16)v1.y, (_Float16)v1.z, (_Float16)v1.w};
        }
        *(half8*)&xp[cell * PSTR + q * 8] = hv;
    }
    if (t > 0 && tid < 240) {
        const _Float16* hb = hprev + (size_t)b * 4096 * 32;
        const int cell = tid >> 2, q = tid & 3;
        const int row = div10(cell), col = cell - row * 10;
        const int gy = py0 + row - 1, gx = px0 + col - 1;
        half8 hv = {0, 0, 0, 0, 0, 0, 0, 0};
        if ((unsigned)gy < 64u && (unsigned)gx < 64u)
            hv = *(const half8*)(hb + ((size_t)(gy * 64 + gx)) * 32 + q * 8);
        *(half8*)&hp[cell * PSTR + q * 8] = hv;
    }

    // bias for this wave's two 16-wide n-tiles: n = w*32 + ntl*16 + l15
    const float bi0 = bias[w * 32 + l15];
    const float bi1 = bias[w * 32 + 16 + l15];

    __syncthreads();

    // ---- MFMA: acc[mt][ntl], px = mt*16 + quad*4 + r, col = w*32 + ntl*16 + l15 ----
    f32x4 acc[2][2];
    acc[0][0] = (f32x4){bi0, bi0, bi0, bi0};
    acc[0][1] = (f32x4){bi1, bi1, bi1, bi1};
    acc[1][0] = acc[0][0];
    acc[1][1] = acc[0][1];

    int pb[2];
    #pragma unroll
    for (int mt = 0; mt < 2; ++mt)        // A-frag row px = mt*16 + l15
        pb[mt] = ((mt * 2 + (l15 >> 3)) * 10 + (l15 & 7)) * PSTR + quad * 8;

    const _Float16* wbx = Wcx + ((size_t)(w * 32 + l15)) * 32 + quad * 8;
    const _Float16* wbh = Wch + ((size_t)(w * 32 + l15)) * 32 + quad * 8;

    #pragma unroll
    for (int tap = 0; tap < 9; ++tap) {
        const int ky = tap / 3, kx = tap - ky * 3;
        const int toff = (ky * 10 + kx) * PSTR;
        const half8 a0 = *(const half8*)&xp[pb[0] + toff];
        const half8 a1 = *(const half8*)&xp[pb[1] + toff];
        #pragma unroll
        for (int ntl = 0; ntl < 2; ++ntl) {
            const half8 bf = *(const half8*)(wbx + tap * 4096 + ntl * 512);
            acc[0][ntl] = __builtin_amdgcn_mfma_f32_16x16x32_f16(a0, bf, acc[0][ntl], 0, 0, 0);
            acc[1][ntl] = __builtin_amdgcn_mfma_f32_16x16x32_f16(a1, bf, acc[1][ntl], 0, 0, 0);
        }
    }
    if (t > 0) {
        #pragma unroll
        for (int tap = 0; tap < 9; ++tap) {
            const int ky = tap / 3, kx = tap - ky * 3;
            const int toff = (ky * 10 + kx) * PSTR;
            const half8 a0 = *(const half8*)&hp[pb[0] + toff];
            const half8 a1 = *(const half8*)&hp[pb[1] + toff];
            #pragma unroll
            for (int ntl = 0; ntl < 2; ++ntl) {
                const half8 bf = *(const half8*)(wbh + tap * 4096 + ntl * 512);
                acc[0][ntl] = __builtin_amdgcn_mfma_f32_16x16x32_f16(a0, bf, acc[0][ntl], 0, 0, 0);
                acc[1][ntl] = __builtin_amdgcn_mfma_f32_16x16x32_f16(a1, bf, acc[1][ntl], 0, 0, 0);
            }
        }
    }

    // ---- write this wave's gate plane to LDS: glds[w][px][f] ----
    #pragma unroll
    for (int mt = 0; mt < 2; ++mt)
        #pragma unroll
        for (int ntl = 0; ntl < 2; ++ntl)
            #pragma unroll
            for (int r = 0; r < 4; ++r) {
                const int px = mt * 16 + quad * 4 + r;
                glds[w * GPL32 + px * GSTR + ntl * 16 + l15] = acc[mt][ntl][r];
            }

    __syncthreads();

    // ---- epilogue: thread owns (px = tid>>3, f = f0..f0+3), coalesced I/O ----
    const int pxt = tid >> 3, f0 = (tid & 7) * 4;
    const int gy = py0 + (pxt >> 3), gx = px0 + (pxt & 7);

    const float4 gav = *(const float4*)&gamma_[f0];
    const float4 bev = *(const float4*)&beta_[f0];
    const float4 mmv = *(const float4*)&mmean[f0];
    const float4 mvv = *(const float4*)&mvar[f0];

    float* cp = csw + (((size_t)b * 128 + tile) * 256 + tid) * 4;
    f32x4 cov = (f32x4){0.f, 0.f, 0.f, 0.f};
    if (t > 0) cov = *(const f32x4*)cp;

    const int gb = pxt * GSTR + f0;
    half4 hv4;
    f32x4 ov, cnv;
    #pragma unroll
    for (int j = 0; j < 4; ++j) {
        const float gi = glds[0 * GPL32 + gb + j];
        const float gf = glds[1 * GPL32 + gb + j];
        const float gc = glds[2 * GPL32 + gb + j];
        const float go = glds[3 * GPL32 + gb + j];
        const float ga = ((const float*)&gav)[j];
        const float mv = ((const float*)&mvv)[j];
        const float inv = ga * rsqrtf(mv + 1e-3f);
        const float bnb = ((const float*)&bev)[j] - ((const float*)&mmv)[j] * inv;
        const float cn = hsig(gf) * cov[j] + hsig(gi) * fast_tanh(gc);
        const float hh = hsig(go) * fast_tanh(cn);
        cnv[j] = cn;
        hv4[j] = (_Float16)hh;
        ov[j] = hh * inv + bnb;
    }

    const size_t pix = ((size_t)(gy * 64 + gx)) * 32 + f0;
    float* oq = out + (((size_t)b * 16 + t) * 4096) * 32;
    *(float4*)(oq + pix) = *(float4*)&ov;         // 16 B coalesced
    if (t < 15) {                                  // h_15 / c_15 never consumed
        _Float16* hq = hnext + (size_t)b * 4096 * 32;
        *(half4*)(hq + pix) = hv4;                 // 8 B coalesced
        *(f32x4*)cp = cnv;                         // 16 B coalesced
    }
}

extern "C" void kernel_launch(void* const* d_in, const int* in_sizes, int n_in,
                              void* d_out, int out_size, void* d_ws, size_t ws_size,
                              hipStream_t stream)
{
    const float* x      = (const float*)d_in[0];
    const float* Wx     = (const float*)d_in[1];
    const float* Wh     = (const float*)d_in[2];
    const float* bias   = (const float*)d_in[3];
    const float* gamma_ = (const float*)d_in[4];
    const float* beta_  = (const float*)d_in[5];
    const float* mmean  = (const float*)d_in[6];
    const float* mvar   = (const float*)d_in[7];
    float* out = (float*)d_out;

    // ws: [h0 2MB][h1 2MB][csw 4MB][Wcx 72KB][Wch 72KB]
    char* wsb = (char*)d_ws;
    _Float16* h0  = (_Float16*)(wsb);
    _Float16* h1  = (_Float16*)(wsb + (1 << 21));
    float*    csw = (float*)(wsb + (1 << 22));
    _Float16* Wcx = (_Float16*)(wsb + (1 << 23));
    _Float16* Wch = (_Float16*)(wsb + (1 << 23) + 73728);

    prep_w<<<dim3(576), dim3(128), 0, stream>>>(Wx, Wh, Wcx, Wch);

    // 16 fused-step launches. No memset: t=0 skips h-conv and starts c=0.
    _Float16* hpr = h0;
    _Float16* hnx = h1;
    for (int t = 0; t < 16; ++t) {
        lstm_step_k<<<dim3(8, 8, 16), 256, 0, stream>>>(
            x, Wcx, Wch, bias, gamma_, beta_, mmean, mvar, hpr, hnx, csw, out, t);
        _Float16* tmp = hpr; hpr = hnx; hnx = tmp;
    }
}